// Round 1
// baseline (1141.163 us; speedup 1.0000x reference)
//
#include <hip/hip_runtime.h>

// Problem constants (validated against in_sizes at launch).
#define DD   64      // channels
#define KK   128     // fused GEMM K = 64 (mean) + 64 (h)
#define XSTR 132     // LDS X-tile row stride (128 + 4 pad -> breaks bank conflicts)

// ---------------------------------------------------------------------------
// degree: one thread per edge, hardware float atomic into deg[dst]
// ---------------------------------------------------------------------------
__global__ __launch_bounds__(256) void deg_kernel(const int* __restrict__ dst,
                                                  float* __restrict__ deg, int E) {
    int e = blockIdx.x * 256 + threadIdx.x;
    if (e < E) unsafeAtomicAdd(&deg[dst[e]], 1.0f);
}

// ---------------------------------------------------------------------------
// scatter-add: one thread per (edge, channel). A 64-lane wave covers one
// edge's full 256 B row -> coalesced gather of h[src], atomic add to agg[dst].
// ---------------------------------------------------------------------------
__global__ __launch_bounds__(256) void scatter_kernel(const float* __restrict__ h,
                                                      const int* __restrict__ src,
                                                      const int* __restrict__ dst,
                                                      float* __restrict__ agg, int E) {
    int tid = blockIdx.x * 256 + threadIdx.x;
    int e = tid >> 6;
    if (e >= E) return;
    int d = tid & 63;
    int s = src[e];
    int t = dst[e];
    unsafeAtomicAdd(&agg[(size_t)t * DD + d], h[(size_t)s * DD + d]);
}

// ---------------------------------------------------------------------------
// Fused per-node update:
//   out = [mean || h] @ [Wl ; Wr] + bl        (K = 128 GEMM, LDS-tiled)
//   MODE 0: h' = relu(LN(out)) + h            (layers 0, 1)
//   MODE 1: h' = l2normalize(out + h)         (layer 2)
// Block = 256 threads, tile = 64 nodes. Thread computes 4 nodes x 4 cols.
// The 16 threads holding one node's row are contiguous lanes -> shfl_xor
// reductions with masks 1,2,4,8.
// ---------------------------------------------------------------------------
template <int MODE>
__global__ __launch_bounds__(256) void node_update(
    const float* __restrict__ h,    // [N,64] layer input (residual source)
    const float* __restrict__ agg,  // [N,64] summed neighbor features
    const float* __restrict__ deg,  // [N]
    const float* __restrict__ Wl,   // [64,64] row-major
    const float* __restrict__ bl,   // [64]
    const float* __restrict__ Wr,   // [64,64]
    const float* __restrict__ g,    // [64] LN gamma (MODE 0 only)
    const float* __restrict__ b,    // [64] LN beta  (MODE 0 only)
    float* __restrict__ out,        // [N,64]
    int nNodes) {
    __shared__ float sW[KK * DD];      // rows 0..63 = Wl, 64..127 = Wr  ([k][c])
    __shared__ float sX[64 * XSTR];    // [n][k]; k<64: mean row, k>=64: h row
    __shared__ float sbl[DD], sg[DD], sb[DD];

    const int t = threadIdx.x;

    // Stage weights (Wl stacked over Wr gives contiguous k-indexing).
    for (int i = t; i < DD * DD; i += 256) {
        sW[i]           = Wl[i];
        sW[DD * DD + i] = Wr[i];
    }
    if (t < DD) {
        sbl[t] = bl[t];
        if (MODE == 0) { sg[t] = g[t]; sb[t] = b[t]; }
    }

    const int nbase = blockIdx.x * 64;

    // Stage X tile: 64 nodes x 128 floats = 2048 float4, coalesced global reads.
    for (int r = 0; r < 8; ++r) {
        int idx  = r * 256 + t;
        int node = idx >> 5;       // 0..63
        int q    = idx & 31;       // which float4 within the 128-float row
        int n    = nbase + node;
        float4 v;
        if (n < nNodes) {
            if (q < 16) {  // mean = agg * 1/max(deg,1)
                v = ((const float4*)(agg + (size_t)n * DD))[q];
                float invd = 1.0f / fmaxf(deg[n], 1.0f);
                v.x *= invd; v.y *= invd; v.z *= invd; v.w *= invd;
            } else {       // raw h
                v = ((const float4*)(h + (size_t)n * DD))[q - 16];
            }
        } else {
            v = make_float4(0.f, 0.f, 0.f, 0.f);
        }
        *(float4*)(&sX[node * XSTR + q * 4]) = v;
    }
    __syncthreads();

    const int c0 = (t & 15) * 4;   // output cols c0..c0+3
    const int n0 = (t >> 4) * 4;   // nodes n0..n0+3 (within tile)

    float acc[4][4];
#pragma unroll
    for (int i = 0; i < 4; ++i)
#pragma unroll
        for (int j = 0; j < 4; ++j) acc[i][j] = sbl[c0 + j];

#pragma unroll 8
    for (int k = 0; k < KK; ++k) {
        const float4 w = *(const float4*)(&sW[k * DD + c0]);
#pragma unroll
        for (int i = 0; i < 4; ++i) {
            float xv = sX[(n0 + i) * XSTR + k];
            acc[i][0] = fmaf(xv, w.x, acc[i][0]);
            acc[i][1] = fmaf(xv, w.y, acc[i][1]);
            acc[i][2] = fmaf(xv, w.z, acc[i][2]);
            acc[i][3] = fmaf(xv, w.w, acc[i][3]);
        }
    }

    // Residual rows come from the LDS tile (h half).
    float res[4][4];
#pragma unroll
    for (int i = 0; i < 4; ++i) {
        float4 rv = *(const float4*)(&sX[(n0 + i) * XSTR + 64 + c0]);
        res[i][0] = rv.x; res[i][1] = rv.y; res[i][2] = rv.z; res[i][3] = rv.w;
    }

#pragma unroll
    for (int i = 0; i < 4; ++i) {
        int nn = nbase + n0 + i;
        float4 o;
        if (MODE == 0) {
            // LayerNorm over the 64-wide row (spread across 16 lanes x 4 regs)
            float s = acc[i][0] + acc[i][1] + acc[i][2] + acc[i][3];
            s += __shfl_xor(s, 1, 64);
            s += __shfl_xor(s, 2, 64);
            s += __shfl_xor(s, 4, 64);
            s += __shfl_xor(s, 8, 64);
            float mu = s * (1.0f / 64.0f);
            float d0 = acc[i][0] - mu, d1 = acc[i][1] - mu,
                  d2 = acc[i][2] - mu, d3 = acc[i][3] - mu;
            float q = d0 * d0 + d1 * d1 + d2 * d2 + d3 * d3;
            q += __shfl_xor(q, 1, 64);
            q += __shfl_xor(q, 2, 64);
            q += __shfl_xor(q, 4, 64);
            q += __shfl_xor(q, 8, 64);
            float rstd = rsqrtf(q * (1.0f / 64.0f) + 1e-5f);
            o.x = fmaxf(d0 * rstd * sg[c0 + 0] + sb[c0 + 0], 0.f) + res[i][0];
            o.y = fmaxf(d1 * rstd * sg[c0 + 1] + sb[c0 + 1], 0.f) + res[i][1];
            o.z = fmaxf(d2 * rstd * sg[c0 + 2] + sb[c0 + 2], 0.f) + res[i][2];
            o.w = fmaxf(d3 * rstd * sg[c0 + 3] + sb[c0 + 3], 0.f) + res[i][3];
        } else {
            // residual add then row-wise L2 normalize
            float y0 = acc[i][0] + res[i][0], y1 = acc[i][1] + res[i][1],
                  y2 = acc[i][2] + res[i][2], y3 = acc[i][3] + res[i][3];
            float q = y0 * y0 + y1 * y1 + y2 * y2 + y3 * y3;
            q += __shfl_xor(q, 1, 64);
            q += __shfl_xor(q, 2, 64);
            q += __shfl_xor(q, 4, 64);
            q += __shfl_xor(q, 8, 64);
            float inv = 1.0f / fmaxf(sqrtf(q), 1e-12f);
            o.x = y0 * inv; o.y = y1 * inv; o.z = y2 * inv; o.w = y3 * inv;
        }
        if (nn < nNodes) *(float4*)(&out[(size_t)nn * DD + c0]) = o;
    }
}

// ---------------------------------------------------------------------------
extern "C" void kernel_launch(void* const* d_in, const int* in_sizes, int n_in,
                              void* d_out, int out_size, void* d_ws, size_t ws_size,
                              hipStream_t stream) {
    const float* x   = (const float*)d_in[0];
    const int*   ei  = (const int*)d_in[1];   // [2, E] int32: row0 = src, row1 = dst
    const float* Wl0 = (const float*)d_in[2];
    const float* bl0 = (const float*)d_in[3];
    const float* Wr0 = (const float*)d_in[4];
    const float* Wl1 = (const float*)d_in[5];
    const float* bl1 = (const float*)d_in[6];
    const float* Wr1 = (const float*)d_in[7];
    const float* Wl2 = (const float*)d_in[8];
    const float* bl2 = (const float*)d_in[9];
    const float* Wr2 = (const float*)d_in[10];
    const float* g0  = (const float*)d_in[11];
    const float* b0  = (const float*)d_in[12];
    const float* g1  = (const float*)d_in[13];
    const float* b1  = (const float*)d_in[14];

    const int N = in_sizes[0] / DD;   // 100000
    const int E = in_sizes[1] / 2;    // 1250000
    const int* src = ei;
    const int* dst = ei + E;

    // Workspace layout (all fp32): A[N*64] | B[N*64] | AGG[N*64] | DEG[N]  ~77 MB
    float* A   = (float*)d_ws;
    float* B   = A + (size_t)N * DD;
    float* AGG = B + (size_t)N * DD;
    float* DEG = AGG + (size_t)N * DD;
    float* out = (float*)d_out;

    const int tiles = (N + 63) / 64;
    const int sgrid = (int)(((long long)E * DD + 255) / 256);
    const int egrid = (E + 255) / 256;

    // degrees: graph is static across the 3 layers -> compute once
    hipMemsetAsync(DEG, 0, (size_t)N * sizeof(float), stream);
    deg_kernel<<<egrid, 256, 0, stream>>>(dst, DEG, E);

    // ---- layer 0: x -> A
    hipMemsetAsync(AGG, 0, (size_t)N * DD * sizeof(float), stream);
    scatter_kernel<<<sgrid, 256, 0, stream>>>(x, src, dst, AGG, E);
    node_update<0><<<tiles, 256, 0, stream>>>(x, AGG, DEG, Wl0, bl0, Wr0, g0, b0, A, N);

    // ---- layer 1: A -> B
    hipMemsetAsync(AGG, 0, (size_t)N * DD * sizeof(float), stream);
    scatter_kernel<<<sgrid, 256, 0, stream>>>(A, src, dst, AGG, E);
    node_update<0><<<tiles, 256, 0, stream>>>(A, AGG, DEG, Wl1, bl1, Wr1, g1, b1, B, N);

    // ---- layer 2: B -> out (residual + L2 normalize)
    hipMemsetAsync(AGG, 0, (size_t)N * DD * sizeof(float), stream);
    scatter_kernel<<<sgrid, 256, 0, stream>>>(B, src, dst, AGG, E);
    node_update<1><<<tiles, 256, 0, stream>>>(B, AGG, DEG, Wl2, bl2, Wr2, nullptr, nullptr, out, N);
}

// Round 2
// 872.266 us; speedup vs baseline: 1.3083x; 1.3083x over previous
//
#include <hip/hip_runtime.h>

#define DD   64      // channels
#define KK   128     // fused GEMM K = 64 (mean) + 64 (h)
#define XSTR 132     // LDS X-tile row stride (128 + 4 pad -> breaks bank conflicts)

// ===========================================================================
// CSR build: histogram -> exclusive scan (two-level) -> fill
// ===========================================================================
__global__ __launch_bounds__(256) void hist_kernel(const int* __restrict__ dst,
                                                   int* __restrict__ degI, int E) {
    int e = blockIdx.x * 256 + threadIdx.x;
    if (e < E) atomicAdd(&degI[dst[e]], 1);
}

// per-block (1024 elems) total
__global__ __launch_bounds__(1024) void scan_reduce(const int* __restrict__ degI,
                                                    int* __restrict__ blockSums, int N) {
    __shared__ int s[1024];
    int t = threadIdx.x;
    int idx = blockIdx.x * 1024 + t;
    s[t] = (idx < N) ? degI[idx] : 0;
    __syncthreads();
    for (int d = 512; d > 0; d >>= 1) {
        if (t < d) s[t] += s[t + d];
        __syncthreads();
    }
    if (t == 0) blockSums[blockIdx.x] = s[0];
}

// exclusive scan of up to 1024 block sums, single block
__global__ __launch_bounds__(1024) void scan_blocksums(int* __restrict__ blockSums, int nb) {
    __shared__ int s[1024];
    int t = threadIdx.x;
    s[t] = (t < nb) ? blockSums[t] : 0;
    __syncthreads();
    for (int d = 1; d < 1024; d <<= 1) {
        int v = (t >= d) ? s[t - d] : 0;
        __syncthreads();
        if (t >= d) s[t] += v;
        __syncthreads();
    }
    if (t < nb) blockSums[t] = (t == 0) ? 0 : s[t - 1];
}

// per-block exclusive scan + block offset -> offsets[] and cursor[] copy
__global__ __launch_bounds__(1024) void scan_final(const int* __restrict__ degI,
                                                   const int* __restrict__ blockSums,
                                                   int* __restrict__ offsets,
                                                   int* __restrict__ cursor,
                                                   int N, int E) {
    __shared__ int s[1024];
    int t = threadIdx.x;
    int idx = blockIdx.x * 1024 + t;
    int val = (idx < N) ? degI[idx] : 0;
    s[t] = val;
    __syncthreads();
    for (int d = 1; d < 1024; d <<= 1) {
        int v = (t >= d) ? s[t - d] : 0;
        __syncthreads();
        if (t >= d) s[t] += v;
        __syncthreads();
    }
    if (idx < N) {
        int ex = blockSums[blockIdx.x] + s[t] - val;   // exclusive
        offsets[idx] = ex;
        cursor[idx]  = ex;
    }
    if (blockIdx.x == 0 && t == 0) offsets[N] = E;
}

__global__ __launch_bounds__(256) void fill_kernel(const int* __restrict__ src,
                                                   const int* __restrict__ dst,
                                                   int* __restrict__ cursor,
                                                   int* __restrict__ csr, int E) {
    int e = blockIdx.x * 256 + threadIdx.x;
    if (e < E) {
        int d = dst[e];
        int pos = atomicAdd(&cursor[d], 1);
        csr[pos] = src[e];
    }
}

// ===========================================================================
// Fused SAGE layer: gather-aggregate (CSR) -> mean -> [mean||h] @ [Wl;Wr] + bl
//   MODE 0: h' = relu(LN(out)) + h
//   MODE 1: h' = l2normalize(out + h)
// Block = 256 threads = 4 waves, tile = 64 dst nodes.
// Aggregation: wave w handles nodes w*16..w*16+15; 64 lanes = 64 channels;
// each neighbor row is one coalesced 256 B gather (L3-resident h).
// ===========================================================================
template <int MODE>
__global__ __launch_bounds__(256) void sage_layer(
    const float* __restrict__ h,       // [N,64] layer input (residual source)
    const int* __restrict__ offsets,   // [N+1]
    const int* __restrict__ csr,       // [E] neighbor src ids grouped by dst
    const float* __restrict__ Wl,      // [64,64] row-major
    const float* __restrict__ bl,      // [64]
    const float* __restrict__ Wr,      // [64,64]
    const float* __restrict__ g,       // [64] LN gamma (MODE 0)
    const float* __restrict__ b,       // [64] LN beta  (MODE 0)
    float* __restrict__ out,           // [N,64]
    int nNodes) {
    __shared__ float sW[KK * DD];      // rows 0..63 = Wl, 64..127 = Wr  ([k][c])
    __shared__ float sX[64 * XSTR];    // [n][k]; k<64: mean row, k>=64: h row
    __shared__ float sbl[DD], sg[DD], sb[DD];

    const int t    = threadIdx.x;
    const int wave = t >> 6;
    const int lane = t & 63;

    // Stage weights.
    for (int i = t; i < DD * DD; i += 256) {
        sW[i]           = Wl[i];
        sW[DD * DD + i] = Wr[i];
    }
    if (t < DD) {
        sbl[t] = bl[t];
        if (MODE == 0) { sg[t] = g[t]; sb[t] = b[t]; }
    }

    const int nbase = blockIdx.x * 64;

    // Stage h rows (k = 64..127 half): 64 nodes x 16 float4, coalesced.
    for (int r = 0; r < 4; ++r) {
        int idx  = r * 256 + t;
        int node = idx >> 4;       // 0..63
        int q    = idx & 15;       // float4 within 64-float row
        int n    = nbase + node;
        float4 v = make_float4(0.f, 0.f, 0.f, 0.f);
        if (n < nNodes) v = ((const float4*)(h + (size_t)n * DD))[q];
        *(float4*)(&sX[node * XSTR + 64 + q * 4]) = v;
    }

    // Gather-aggregate into the mean half. lane = channel.
#pragma unroll 1
    for (int i = 0; i < 16; ++i) {
        int node = wave * 16 + i;
        int nn   = nbase + node;
        float acc = 0.f;
        if (nn < nNodes) {
            int off0 = offsets[nn];
            int off1 = offsets[nn + 1];
            int j = off0;
            for (; j + 3 < off1; j += 4) {
                int s0 = csr[j], s1 = csr[j + 1], s2 = csr[j + 2], s3 = csr[j + 3];
                float v0 = h[(size_t)s0 * DD + lane];
                float v1 = h[(size_t)s1 * DD + lane];
                float v2 = h[(size_t)s2 * DD + lane];
                float v3 = h[(size_t)s3 * DD + lane];
                acc += (v0 + v1) + (v2 + v3);
            }
            for (; j < off1; ++j) acc += h[(size_t)csr[j] * DD + lane];
            acc *= 1.0f / fmaxf((float)(off1 - off0), 1.0f);
        }
        sX[node * XSTR + lane] = acc;
    }
    __syncthreads();

    const int c0 = (t & 15) * 4;   // output cols c0..c0+3
    const int n0 = (t >> 4) * 4;   // nodes n0..n0+3 (within tile)

    float acc[4][4];
#pragma unroll
    for (int i = 0; i < 4; ++i)
#pragma unroll
        for (int j = 0; j < 4; ++j) acc[i][j] = sbl[c0 + j];

#pragma unroll 8
    for (int k = 0; k < KK; ++k) {
        const float4 w = *(const float4*)(&sW[k * DD + c0]);
#pragma unroll
        for (int i = 0; i < 4; ++i) {
            float xv = sX[(n0 + i) * XSTR + k];
            acc[i][0] = fmaf(xv, w.x, acc[i][0]);
            acc[i][1] = fmaf(xv, w.y, acc[i][1]);
            acc[i][2] = fmaf(xv, w.z, acc[i][2]);
            acc[i][3] = fmaf(xv, w.w, acc[i][3]);
        }
    }

    // Residual rows from the LDS h half.
    float res[4][4];
#pragma unroll
    for (int i = 0; i < 4; ++i) {
        float4 rv = *(const float4*)(&sX[(n0 + i) * XSTR + 64 + c0]);
        res[i][0] = rv.x; res[i][1] = rv.y; res[i][2] = rv.z; res[i][3] = rv.w;
    }

#pragma unroll
    for (int i = 0; i < 4; ++i) {
        int nn = nbase + n0 + i;
        float4 o;
        if (MODE == 0) {
            float s = acc[i][0] + acc[i][1] + acc[i][2] + acc[i][3];
            s += __shfl_xor(s, 1, 64);
            s += __shfl_xor(s, 2, 64);
            s += __shfl_xor(s, 4, 64);
            s += __shfl_xor(s, 8, 64);
            float mu = s * (1.0f / 64.0f);
            float d0 = acc[i][0] - mu, d1 = acc[i][1] - mu,
                  d2 = acc[i][2] - mu, d3 = acc[i][3] - mu;
            float q = d0 * d0 + d1 * d1 + d2 * d2 + d3 * d3;
            q += __shfl_xor(q, 1, 64);
            q += __shfl_xor(q, 2, 64);
            q += __shfl_xor(q, 4, 64);
            q += __shfl_xor(q, 8, 64);
            float rstd = rsqrtf(q * (1.0f / 64.0f) + 1e-5f);
            o.x = fmaxf(d0 * rstd * sg[c0 + 0] + sb[c0 + 0], 0.f) + res[i][0];
            o.y = fmaxf(d1 * rstd * sg[c0 + 1] + sb[c0 + 1], 0.f) + res[i][1];
            o.z = fmaxf(d2 * rstd * sg[c0 + 2] + sb[c0 + 2], 0.f) + res[i][2];
            o.w = fmaxf(d3 * rstd * sg[c0 + 3] + sb[c0 + 3], 0.f) + res[i][3];
        } else {
            float y0 = acc[i][0] + res[i][0], y1 = acc[i][1] + res[i][1],
                  y2 = acc[i][2] + res[i][2], y3 = acc[i][3] + res[i][3];
            float q = y0 * y0 + y1 * y1 + y2 * y2 + y3 * y3;
            q += __shfl_xor(q, 1, 64);
            q += __shfl_xor(q, 2, 64);
            q += __shfl_xor(q, 4, 64);
            q += __shfl_xor(q, 8, 64);
            float inv = 1.0f / fmaxf(sqrtf(q), 1e-12f);
            o.x = y0 * inv; o.y = y1 * inv; o.z = y2 * inv; o.w = y3 * inv;
        }
        if (nn < nNodes) *(float4*)(&out[(size_t)nn * DD + c0]) = o;
    }
}

// ===========================================================================
extern "C" void kernel_launch(void* const* d_in, const int* in_sizes, int n_in,
                              void* d_out, int out_size, void* d_ws, size_t ws_size,
                              hipStream_t stream) {
    const float* x   = (const float*)d_in[0];
    const int*   ei  = (const int*)d_in[1];   // [2, E] int32: row0 = src, row1 = dst
    const float* Wl0 = (const float*)d_in[2];
    const float* bl0 = (const float*)d_in[3];
    const float* Wr0 = (const float*)d_in[4];
    const float* Wl1 = (const float*)d_in[5];
    const float* bl1 = (const float*)d_in[6];
    const float* Wr1 = (const float*)d_in[7];
    const float* Wl2 = (const float*)d_in[8];
    const float* bl2 = (const float*)d_in[9];
    const float* Wr2 = (const float*)d_in[10];
    const float* g0  = (const float*)d_in[11];
    const float* b0  = (const float*)d_in[12];
    const float* g1  = (const float*)d_in[13];
    const float* b1  = (const float*)d_in[14];

    const int N = in_sizes[0] / DD;   // 100000
    const int E = in_sizes[1] / 2;    // 1250000
    const int* src = ei;
    const int* dst = ei + E;

    // Workspace: A[N*64] f32 | B[N*64] f32 | degI[N] | offsets[N+1] | cursor[N]
    //            | blockSums[1024] | csr[E]           (~57 MB total)
    float* A       = (float*)d_ws;
    float* B       = A + (size_t)N * DD;
    int*   degI    = (int*)(B + (size_t)N * DD);
    int*   offsets = degI + N;
    int*   cursor  = offsets + (N + 1);
    int*   bsums   = cursor + N;
    int*   csr     = bsums + 1024;
    float* out     = (float*)d_out;

    const int tiles = (N + 63) / 64;
    const int egrid = (E + 255) / 256;
    const int nb    = (N + 1023) / 1024;

    // ---- CSR build (once; graph static across the 3 layers)
    hipMemsetAsync(degI, 0, (size_t)N * sizeof(int), stream);
    hist_kernel<<<egrid, 256, 0, stream>>>(dst, degI, E);
    scan_reduce<<<nb, 1024, 0, stream>>>(degI, bsums, N);
    scan_blocksums<<<1, 1024, 0, stream>>>(bsums, nb);
    scan_final<<<nb, 1024, 0, stream>>>(degI, bsums, offsets, cursor, N, E);
    fill_kernel<<<egrid, 256, 0, stream>>>(src, dst, cursor, csr, E);

    // ---- 3 fused layers
    sage_layer<0><<<tiles, 256, 0, stream>>>(x, offsets, csr, Wl0, bl0, Wr0, g0, b0, A, N);
    sage_layer<0><<<tiles, 256, 0, stream>>>(A, offsets, csr, Wl1, bl1, Wr1, g1, b1, B, N);
    sage_layer<1><<<tiles, 256, 0, stream>>>(B, offsets, csr, Wl2, bl2, Wr2, nullptr, nullptr, out, N);
}

// Round 3
// 524.390 us; speedup vs baseline: 2.1762x; 1.6634x over previous
//
#include <hip/hip_runtime.h>

#define DD   64      // channels
#define KK   128     // fused GEMM K = 64 (mean) + 64 (h)
#define XSTR 132     // LDS X-tile row stride (128 + 4 pad -> breaks bank conflicts)

// ===========================================================================
// CSR build: histogram -> exclusive scan (two-level) -> fill
// ===========================================================================
__global__ __launch_bounds__(256) void hist_kernel(const int* __restrict__ dst,
                                                   int* __restrict__ degI, int E) {
    int e = blockIdx.x * 256 + threadIdx.x;
    if (e < E) atomicAdd(&degI[dst[e]], 1);
}

__global__ __launch_bounds__(1024) void scan_reduce(const int* __restrict__ degI,
                                                    int* __restrict__ blockSums, int N) {
    __shared__ int s[1024];
    int t = threadIdx.x;
    int idx = blockIdx.x * 1024 + t;
    s[t] = (idx < N) ? degI[idx] : 0;
    __syncthreads();
    for (int d = 512; d > 0; d >>= 1) {
        if (t < d) s[t] += s[t + d];
        __syncthreads();
    }
    if (t == 0) blockSums[blockIdx.x] = s[0];
}

__global__ __launch_bounds__(1024) void scan_blocksums(int* __restrict__ blockSums, int nb) {
    __shared__ int s[1024];
    int t = threadIdx.x;
    s[t] = (t < nb) ? blockSums[t] : 0;
    __syncthreads();
    for (int d = 1; d < 1024; d <<= 1) {
        int v = (t >= d) ? s[t - d] : 0;
        __syncthreads();
        if (t >= d) s[t] += v;
        __syncthreads();
    }
    if (t < nb) blockSums[t] = (t == 0) ? 0 : s[t - 1];
}

__global__ __launch_bounds__(1024) void scan_final(const int* __restrict__ degI,
                                                   const int* __restrict__ blockSums,
                                                   int* __restrict__ offsets,
                                                   int* __restrict__ cursor,
                                                   int N, int E) {
    __shared__ int s[1024];
    int t = threadIdx.x;
    int idx = blockIdx.x * 1024 + t;
    int val = (idx < N) ? degI[idx] : 0;
    s[t] = val;
    __syncthreads();
    for (int d = 1; d < 1024; d <<= 1) {
        int v = (t >= d) ? s[t - d] : 0;
        __syncthreads();
        if (t >= d) s[t] += v;
        __syncthreads();
    }
    if (idx < N) {
        int ex = blockSums[blockIdx.x] + s[t] - val;   // exclusive
        offsets[idx] = ex;
        cursor[idx]  = ex;
    }
    if (blockIdx.x == 0 && t == 0) offsets[N] = E;
}

__global__ __launch_bounds__(256) void fill_kernel(const int* __restrict__ src,
                                                   const int* __restrict__ dst,
                                                   int* __restrict__ cursor,
                                                   int* __restrict__ csr, int E) {
    int e = blockIdx.x * 256 + threadIdx.x;
    if (e < E) {
        int d = dst[e];
        int pos = atomicAdd(&cursor[d], 1);
        csr[pos] = src[e];
    }
}

// ===========================================================================
// Aggregation: one WAVE per dst node, no LDS -> high occupancy.
// 64 lanes = 4 groups x 16. Group g gathers neighbor (j+s*4+g) as float4
// (lane q covers channels q*4..q*4+3); 4-deep unroll -> up to 16 rows of
// 256 B in flight per wave. Cross-group reduce via shfl_xor(16,32).
// Writes the MEAN row (divided by deg) to agg.
// ===========================================================================
__global__ __launch_bounds__(256) void aggregate_kernel(
    const float* __restrict__ h,       // [N,64]
    const int* __restrict__ offsets,   // [N+1]
    const int* __restrict__ csr,       // [E]
    float* __restrict__ agg,           // [N,64] <- mean of neighbor rows
    int N) {
    int w = (blockIdx.x * 256 + threadIdx.x) >> 6;   // global wave id = node
    if (w >= N) return;
    const int lane = threadIdx.x & 63;
    const int g    = lane >> 4;        // neighbor sub-slot 0..3
    const int q    = lane & 15;        // float4 index within row

    const int off0 = offsets[w];
    const int off1 = offsets[w + 1];

    float4 acc = make_float4(0.f, 0.f, 0.f, 0.f);
    for (int j = off0; j < off1; j += 16) {
#pragma unroll
        for (int s = 0; s < 4; ++s) {
            int idx = j + s * 4 + g;
            if (idx < off1) {
                int sn = csr[idx];
                float4 v = ((const float4*)(h + (size_t)sn * DD))[q];
                acc.x += v.x; acc.y += v.y; acc.z += v.z; acc.w += v.w;
            }
        }
    }
    // reduce across the 4 groups
    acc.x += __shfl_xor(acc.x, 16, 64); acc.y += __shfl_xor(acc.y, 16, 64);
    acc.z += __shfl_xor(acc.z, 16, 64); acc.w += __shfl_xor(acc.w, 16, 64);
    acc.x += __shfl_xor(acc.x, 32, 64); acc.y += __shfl_xor(acc.y, 32, 64);
    acc.z += __shfl_xor(acc.z, 32, 64); acc.w += __shfl_xor(acc.w, 32, 64);

    if (lane < 16) {
        float invd = 1.0f / fmaxf((float)(off1 - off0), 1.0f);
        acc.x *= invd; acc.y *= invd; acc.z *= invd; acc.w *= invd;
        *(float4*)(&agg[(size_t)w * DD + q * 4]) = acc;
    }
}

// ===========================================================================
// Fused per-node update: out = [mean || h] @ [Wl ; Wr] + bl
//   MODE 0: h' = relu(LN(out)) + h
//   MODE 1: h' = l2normalize(out + h)
// Block = 256 threads, tile = 64 nodes; thread computes 4 nodes x 4 cols.
// ===========================================================================
template <int MODE>
__global__ __launch_bounds__(256) void node_update(
    const float* __restrict__ h,    // [N,64] layer input (residual source)
    const float* __restrict__ mean, // [N,64] precomputed neighbor mean
    const float* __restrict__ Wl,   // [64,64] row-major
    const float* __restrict__ bl,   // [64]
    const float* __restrict__ Wr,   // [64,64]
    const float* __restrict__ g,    // [64] LN gamma (MODE 0)
    const float* __restrict__ b,    // [64] LN beta  (MODE 0)
    float* __restrict__ out,        // [N,64]
    int nNodes) {
    __shared__ float sW[KK * DD];      // rows 0..63 = Wl, 64..127 = Wr  ([k][c])
    __shared__ float sX[64 * XSTR];    // [n][k]; k<64: mean row, k>=64: h row
    __shared__ float sbl[DD], sg[DD], sb[DD];

    const int t = threadIdx.x;

    for (int i = t; i < DD * DD; i += 256) {
        sW[i]           = Wl[i];
        sW[DD * DD + i] = Wr[i];
    }
    if (t < DD) {
        sbl[t] = bl[t];
        if (MODE == 0) { sg[t] = g[t]; sb[t] = b[t]; }
    }

    const int nbase = blockIdx.x * 64;

    // Stage X tile: 64 nodes x 128 floats = 2048 float4, coalesced.
    for (int r = 0; r < 8; ++r) {
        int idx  = r * 256 + t;
        int node = idx >> 5;       // 0..63
        int q    = idx & 31;       // float4 within the 128-float row
        int n    = nbase + node;
        float4 v = make_float4(0.f, 0.f, 0.f, 0.f);
        if (n < nNodes) {
            v = (q < 16) ? ((const float4*)(mean + (size_t)n * DD))[q]
                         : ((const float4*)(h    + (size_t)n * DD))[q - 16];
        }
        *(float4*)(&sX[node * XSTR + q * 4]) = v;
    }
    __syncthreads();

    const int c0 = (t & 15) * 4;   // output cols c0..c0+3
    const int n0 = (t >> 4) * 4;   // nodes n0..n0+3 (within tile)

    float acc[4][4];
#pragma unroll
    for (int i = 0; i < 4; ++i)
#pragma unroll
        for (int j = 0; j < 4; ++j) acc[i][j] = sbl[c0 + j];

#pragma unroll 8
    for (int k = 0; k < KK; ++k) {
        const float4 w = *(const float4*)(&sW[k * DD + c0]);
#pragma unroll
        for (int i = 0; i < 4; ++i) {
            float xv = sX[(n0 + i) * XSTR + k];
            acc[i][0] = fmaf(xv, w.x, acc[i][0]);
            acc[i][1] = fmaf(xv, w.y, acc[i][1]);
            acc[i][2] = fmaf(xv, w.z, acc[i][2]);
            acc[i][3] = fmaf(xv, w.w, acc[i][3]);
        }
    }

    float res[4][4];
#pragma unroll
    for (int i = 0; i < 4; ++i) {
        float4 rv = *(const float4*)(&sX[(n0 + i) * XSTR + 64 + c0]);
        res[i][0] = rv.x; res[i][1] = rv.y; res[i][2] = rv.z; res[i][3] = rv.w;
    }

#pragma unroll
    for (int i = 0; i < 4; ++i) {
        int nn = nbase + n0 + i;
        float4 o;
        if (MODE == 0) {
            float s = acc[i][0] + acc[i][1] + acc[i][2] + acc[i][3];
            s += __shfl_xor(s, 1, 64);
            s += __shfl_xor(s, 2, 64);
            s += __shfl_xor(s, 4, 64);
            s += __shfl_xor(s, 8, 64);
            float mu = s * (1.0f / 64.0f);
            float d0 = acc[i][0] - mu, d1 = acc[i][1] - mu,
                  d2 = acc[i][2] - mu, d3 = acc[i][3] - mu;
            float qq = d0 * d0 + d1 * d1 + d2 * d2 + d3 * d3;
            qq += __shfl_xor(qq, 1, 64);
            qq += __shfl_xor(qq, 2, 64);
            qq += __shfl_xor(qq, 4, 64);
            qq += __shfl_xor(qq, 8, 64);
            float rstd = rsqrtf(qq * (1.0f / 64.0f) + 1e-5f);
            o.x = fmaxf(d0 * rstd * sg[c0 + 0] + sb[c0 + 0], 0.f) + res[i][0];
            o.y = fmaxf(d1 * rstd * sg[c0 + 1] + sb[c0 + 1], 0.f) + res[i][1];
            o.z = fmaxf(d2 * rstd * sg[c0 + 2] + sb[c0 + 2], 0.f) + res[i][2];
            o.w = fmaxf(d3 * rstd * sg[c0 + 3] + sb[c0 + 3], 0.f) + res[i][3];
        } else {
            float y0 = acc[i][0] + res[i][0], y1 = acc[i][1] + res[i][1],
                  y2 = acc[i][2] + res[i][2], y3 = acc[i][3] + res[i][3];
            float qq = y0 * y0 + y1 * y1 + y2 * y2 + y3 * y3;
            qq += __shfl_xor(qq, 1, 64);
            qq += __shfl_xor(qq, 2, 64);
            qq += __shfl_xor(qq, 4, 64);
            qq += __shfl_xor(qq, 8, 64);
            float inv = 1.0f / fmaxf(sqrtf(qq), 1e-12f);
            o.x = y0 * inv; o.y = y1 * inv; o.z = y2 * inv; o.w = y3 * inv;
        }
        if (nn < nNodes) *(float4*)(&out[(size_t)nn * DD + c0]) = o;
    }
}

// ===========================================================================
extern "C" void kernel_launch(void* const* d_in, const int* in_sizes, int n_in,
                              void* d_out, int out_size, void* d_ws, size_t ws_size,
                              hipStream_t stream) {
    const float* x   = (const float*)d_in[0];
    const int*   ei  = (const int*)d_in[1];   // [2, E] int32: row0 = src, row1 = dst
    const float* Wl0 = (const float*)d_in[2];
    const float* bl0 = (const float*)d_in[3];
    const float* Wr0 = (const float*)d_in[4];
    const float* Wl1 = (const float*)d_in[5];
    const float* bl1 = (const float*)d_in[6];
    const float* Wr1 = (const float*)d_in[7];
    const float* Wl2 = (const float*)d_in[8];
    const float* bl2 = (const float*)d_in[9];
    const float* Wr2 = (const float*)d_in[10];
    const float* g0  = (const float*)d_in[11];
    const float* b0  = (const float*)d_in[12];
    const float* g1  = (const float*)d_in[13];
    const float* b1  = (const float*)d_in[14];

    const int N = in_sizes[0] / DD;   // 100000
    const int E = in_sizes[1] / 2;    // 1250000
    const int* src = ei;
    const int* dst = ei + E;

    // Workspace: A[N*64] | B[N*64] | AGG[N*64] f32 | degI[N] | offsets[N+1]
    //            | cursor[N] | blockSums[1024] | csr[E]
    float* A       = (float*)d_ws;
    float* B       = A + (size_t)N * DD;
    float* AGG     = B + (size_t)N * DD;
    int*   degI    = (int*)(AGG + (size_t)N * DD);
    int*   offsets = degI + N;
    int*   cursor  = offsets + (N + 1);
    int*   bsums   = cursor + N;
    int*   csr     = bsums + 1024;
    float* out     = (float*)d_out;

    const int tiles = (N + 63) / 64;
    const int egrid = (E + 255) / 256;
    const int nb    = (N + 1023) / 1024;
    const int agrid = (N + 3) / 4;    // 4 waves/block, 1 node/wave

    // ---- CSR build (once; graph static across the 3 layers)
    hipMemsetAsync(degI, 0, (size_t)N * sizeof(int), stream);
    hist_kernel<<<egrid, 256, 0, stream>>>(dst, degI, E);
    scan_reduce<<<nb, 1024, 0, stream>>>(degI, bsums, N);
    scan_blocksums<<<1, 1024, 0, stream>>>(bsums, nb);
    scan_final<<<nb, 1024, 0, stream>>>(degI, bsums, offsets, cursor, N, E);
    fill_kernel<<<egrid, 256, 0, stream>>>(src, dst, cursor, csr, E);

    // ---- 3 layers: gather-mean, then fused GEMM + epilogue
    aggregate_kernel<<<agrid, 256, 0, stream>>>(x, offsets, csr, AGG, N);
    node_update<0><<<tiles, 256, 0, stream>>>(x, AGG, Wl0, bl0, Wr0, g0, b0, A, N);

    aggregate_kernel<<<agrid, 256, 0, stream>>>(A, offsets, csr, AGG, N);
    node_update<0><<<tiles, 256, 0, stream>>>(A, AGG, Wl1, bl1, Wr1, g1, b1, B, N);

    aggregate_kernel<<<agrid, 256, 0, stream>>>(B, offsets, csr, AGG, N);
    node_update<1><<<tiles, 256, 0, stream>>>(B, AGG, Wl2, bl2, Wr2, nullptr, nullptr, out, N);
}

// Round 4
// 483.773 us; speedup vs baseline: 2.3589x; 1.0840x over previous
//
#include <hip/hip_runtime.h>

#define DD   64      // channels
#define KK   128     // fused GEMM K = 64 (mean) + 64 (h)
#define XSTR 132     // LDS X-tile row stride (128 + 4 pad -> breaks bank conflicts)

// ===========================================================================
// CSR build: histogram(+rank) -> exclusive scan (two-level) -> fill (no atomic)
// ===========================================================================
__global__ __launch_bounds__(256) void hist_kernel(const int* __restrict__ dst,
                                                   int* __restrict__ degI,
                                                   int* __restrict__ rank, int E) {
    int e = blockIdx.x * 256 + threadIdx.x;
    if (e < E) rank[e] = atomicAdd(&degI[dst[e]], 1);
}

__global__ __launch_bounds__(1024) void scan_reduce(const int* __restrict__ degI,
                                                    int* __restrict__ blockSums, int N) {
    __shared__ int s[1024];
    int t = threadIdx.x;
    int idx = blockIdx.x * 1024 + t;
    s[t] = (idx < N) ? degI[idx] : 0;
    __syncthreads();
    for (int d = 512; d > 0; d >>= 1) {
        if (t < d) s[t] += s[t + d];
        __syncthreads();
    }
    if (t == 0) blockSums[blockIdx.x] = s[0];
}

__global__ __launch_bounds__(1024) void scan_blocksums(int* __restrict__ blockSums, int nb) {
    __shared__ int s[1024];
    int t = threadIdx.x;
    s[t] = (t < nb) ? blockSums[t] : 0;
    __syncthreads();
    for (int d = 1; d < 1024; d <<= 1) {
        int v = (t >= d) ? s[t - d] : 0;
        __syncthreads();
        if (t >= d) s[t] += v;
        __syncthreads();
    }
    if (t < nb) blockSums[t] = (t == 0) ? 0 : s[t - 1];
}

__global__ __launch_bounds__(1024) void scan_final(const int* __restrict__ degI,
                                                   const int* __restrict__ blockSums,
                                                   int* __restrict__ offsets,
                                                   int N, int E) {
    __shared__ int s[1024];
    int t = threadIdx.x;
    int idx = blockIdx.x * 1024 + t;
    int val = (idx < N) ? degI[idx] : 0;
    s[t] = val;
    __syncthreads();
    for (int d = 1; d < 1024; d <<= 1) {
        int v = (t >= d) ? s[t - d] : 0;
        __syncthreads();
        if (t >= d) s[t] += v;
        __syncthreads();
    }
    if (idx < N) offsets[idx] = blockSums[blockIdx.x] + s[t] - val;   // exclusive
    if (blockIdx.x == 0 && t == 0) offsets[N] = E;
}

__global__ __launch_bounds__(256) void fill_kernel(const int* __restrict__ src,
                                                   const int* __restrict__ dst,
                                                   const int* __restrict__ offsets,
                                                   const int* __restrict__ rank,
                                                   int* __restrict__ csr, int E) {
    int e = blockIdx.x * 256 + threadIdx.x;
    if (e < E) {
        int pos = offsets[dst[e]] + rank[e];
        __builtin_nontemporal_store(src[e], &csr[pos]);
    }
}

// ===========================================================================
// Aggregation: one 16-LANE GROUP per dst node (4 nodes/wave, 16/block).
// Lane q owns float4 chunk q of the 256 B row. Neighbors consumed in
// predicated batches of 8 -> 8 independent gathers in flight per lane.
// No cross-lane reduction. Writes the MEAN row to agg (fully coalesced).
// ===========================================================================
__global__ __launch_bounds__(256) void aggregate_kernel(
    const float* __restrict__ h,       // [N,64]
    const int* __restrict__ offsets,   // [N+1]
    const int* __restrict__ csr,       // [E]
    float* __restrict__ agg,           // [N,64] <- mean of neighbor rows
    int N) {
    int node = (blockIdx.x * 256 + threadIdx.x) >> 4;   // global group id
    if (node >= N) return;
    const int q = threadIdx.x & 15;    // float4 index within row

    const int off0 = offsets[node];
    const int off1 = offsets[node + 1];

    float4 acc = make_float4(0.f, 0.f, 0.f, 0.f);
    for (int j = off0; j < off1; j += 8) {
        float4 v[8];
#pragma unroll
        for (int s = 0; s < 8; ++s) {
            v[s] = make_float4(0.f, 0.f, 0.f, 0.f);
            int idx = j + s;
            if (idx < off1) {
                int sn = __builtin_nontemporal_load(&csr[idx]);
                v[s] = ((const float4*)(h + (size_t)sn * DD))[q];
            }
        }
        acc.x += ((v[0].x + v[1].x) + (v[2].x + v[3].x)) + ((v[4].x + v[5].x) + (v[6].x + v[7].x));
        acc.y += ((v[0].y + v[1].y) + (v[2].y + v[3].y)) + ((v[4].y + v[5].y) + (v[6].y + v[7].y));
        acc.z += ((v[0].z + v[1].z) + (v[2].z + v[3].z)) + ((v[4].z + v[5].z) + (v[6].z + v[7].z));
        acc.w += ((v[0].w + v[1].w) + (v[2].w + v[3].w)) + ((v[4].w + v[5].w) + (v[6].w + v[7].w));
    }
    float invd = 1.0f / fmaxf((float)(off1 - off0), 1.0f);
    acc.x *= invd; acc.y *= invd; acc.z *= invd; acc.w *= invd;
    *(float4*)(&agg[(size_t)node * DD + q * 4]) = acc;
}

// ===========================================================================
// Fused per-node update: out = [mean || h] @ [Wl ; Wr] + bl
//   MODE 0: h' = relu(LN(out)) + h
//   MODE 1: h' = l2normalize(out + h)
// Block = 256 threads, tile = 64 nodes; thread computes 4 nodes x 4 cols.
// ===========================================================================
template <int MODE>
__global__ __launch_bounds__(256) void node_update(
    const float* __restrict__ h,    // [N,64] layer input (residual source)
    const float* __restrict__ mean, // [N,64] precomputed neighbor mean
    const float* __restrict__ Wl,   // [64,64] row-major
    const float* __restrict__ bl,   // [64]
    const float* __restrict__ Wr,   // [64,64]
    const float* __restrict__ g,    // [64] LN gamma (MODE 0)
    const float* __restrict__ b,    // [64] LN beta  (MODE 0)
    float* __restrict__ out,        // [N,64]
    int nNodes) {
    __shared__ float sW[KK * DD];      // rows 0..63 = Wl, 64..127 = Wr  ([k][c])
    __shared__ float sX[64 * XSTR];    // [n][k]; k<64: mean row, k>=64: h row
    __shared__ float sbl[DD], sg[DD], sb[DD];

    const int t = threadIdx.x;

    for (int i = t; i < DD * DD; i += 256) {
        sW[i]           = Wl[i];
        sW[DD * DD + i] = Wr[i];
    }
    if (t < DD) {
        sbl[t] = bl[t];
        if (MODE == 0) { sg[t] = g[t]; sb[t] = b[t]; }
    }

    const int nbase = blockIdx.x * 64;

    for (int r = 0; r < 8; ++r) {
        int idx  = r * 256 + t;
        int node = idx >> 5;       // 0..63
        int q    = idx & 31;       // float4 within the 128-float row
        int n    = nbase + node;
        float4 v = make_float4(0.f, 0.f, 0.f, 0.f);
        if (n < nNodes) {
            v = (q < 16) ? ((const float4*)(mean + (size_t)n * DD))[q]
                         : ((const float4*)(h    + (size_t)n * DD))[q - 16];
        }
        *(float4*)(&sX[node * XSTR + q * 4]) = v;
    }
    __syncthreads();

    const int c0 = (t & 15) * 4;   // output cols c0..c0+3
    const int n0 = (t >> 4) * 4;   // nodes n0..n0+3 (within tile)

    float acc[4][4];
#pragma unroll
    for (int i = 0; i < 4; ++i)
#pragma unroll
        for (int j = 0; j < 4; ++j) acc[i][j] = sbl[c0 + j];

#pragma unroll 8
    for (int k = 0; k < KK; ++k) {
        const float4 w = *(const float4*)(&sW[k * DD + c0]);
#pragma unroll
        for (int i = 0; i < 4; ++i) {
            float xv = sX[(n0 + i) * XSTR + k];
            acc[i][0] = fmaf(xv, w.x, acc[i][0]);
            acc[i][1] = fmaf(xv, w.y, acc[i][1]);
            acc[i][2] = fmaf(xv, w.z, acc[i][2]);
            acc[i][3] = fmaf(xv, w.w, acc[i][3]);
        }
    }

    float res[4][4];
#pragma unroll
    for (int i = 0; i < 4; ++i) {
        float4 rv = *(const float4*)(&sX[(n0 + i) * XSTR + 64 + c0]);
        res[i][0] = rv.x; res[i][1] = rv.y; res[i][2] = rv.z; res[i][3] = rv.w;
    }

#pragma unroll
    for (int i = 0; i < 4; ++i) {
        int nn = nbase + n0 + i;
        float4 o;
        if (MODE == 0) {
            float s = acc[i][0] + acc[i][1] + acc[i][2] + acc[i][3];
            s += __shfl_xor(s, 1, 64);
            s += __shfl_xor(s, 2, 64);
            s += __shfl_xor(s, 4, 64);
            s += __shfl_xor(s, 8, 64);
            float mu = s * (1.0f / 64.0f);
            float d0 = acc[i][0] - mu, d1 = acc[i][1] - mu,
                  d2 = acc[i][2] - mu, d3 = acc[i][3] - mu;
            float qq = d0 * d0 + d1 * d1 + d2 * d2 + d3 * d3;
            qq += __shfl_xor(qq, 1, 64);
            qq += __shfl_xor(qq, 2, 64);
            qq += __shfl_xor(qq, 4, 64);
            qq += __shfl_xor(qq, 8, 64);
            float rstd = rsqrtf(qq * (1.0f / 64.0f) + 1e-5f);
            o.x = fmaxf(d0 * rstd * sg[c0 + 0] + sb[c0 + 0], 0.f) + res[i][0];
            o.y = fmaxf(d1 * rstd * sg[c0 + 1] + sb[c0 + 1], 0.f) + res[i][1];
            o.z = fmaxf(d2 * rstd * sg[c0 + 2] + sb[c0 + 2], 0.f) + res[i][2];
            o.w = fmaxf(d3 * rstd * sg[c0 + 3] + sb[c0 + 3], 0.f) + res[i][3];
        } else {
            float y0 = acc[i][0] + res[i][0], y1 = acc[i][1] + res[i][1],
                  y2 = acc[i][2] + res[i][2], y3 = acc[i][3] + res[i][3];
            float qq = y0 * y0 + y1 * y1 + y2 * y2 + y3 * y3;
            qq += __shfl_xor(qq, 1, 64);
            qq += __shfl_xor(qq, 2, 64);
            qq += __shfl_xor(qq, 4, 64);
            qq += __shfl_xor(qq, 8, 64);
            float inv = 1.0f / fmaxf(sqrtf(qq), 1e-12f);
            o.x = y0 * inv; o.y = y1 * inv; o.z = y2 * inv; o.w = y3 * inv;
        }
        if (nn < nNodes) *(float4*)(&out[(size_t)nn * DD + c0]) = o;
    }
}

// ===========================================================================
extern "C" void kernel_launch(void* const* d_in, const int* in_sizes, int n_in,
                              void* d_out, int out_size, void* d_ws, size_t ws_size,
                              hipStream_t stream) {
    const float* x   = (const float*)d_in[0];
    const int*   ei  = (const int*)d_in[1];   // [2, E] int32: row0 = src, row1 = dst
    const float* Wl0 = (const float*)d_in[2];
    const float* bl0 = (const float*)d_in[3];
    const float* Wr0 = (const float*)d_in[4];
    const float* Wl1 = (const float*)d_in[5];
    const float* bl1 = (const float*)d_in[6];
    const float* Wr1 = (const float*)d_in[7];
    const float* Wl2 = (const float*)d_in[8];
    const float* bl2 = (const float*)d_in[9];
    const float* Wr2 = (const float*)d_in[10];
    const float* g0  = (const float*)d_in[11];
    const float* b0  = (const float*)d_in[12];
    const float* g1  = (const float*)d_in[13];
    const float* b1  = (const float*)d_in[14];

    const int N = in_sizes[0] / DD;   // 100000
    const int E = in_sizes[1] / 2;    // 1250000
    const int* src = ei;
    const int* dst = ei + E;

    // Workspace: A[N*64] | B[N*64] | AGG[N*64] f32 | degI[N] | offsets[N+1]
    //            | blockSums[1024] | csr[E].  rank[E] aliases AGG (AGG is
    //            only written by aggregate_kernel, after fill consumed rank).
    float* A       = (float*)d_ws;
    float* B       = A + (size_t)N * DD;
    float* AGG     = B + (size_t)N * DD;
    int*   rank    = (int*)AGG;
    int*   degI    = (int*)(AGG + (size_t)N * DD);
    int*   offsets = degI + N;
    int*   bsums   = offsets + (N + 1);
    int*   csr     = bsums + 1024;
    float* out     = (float*)d_out;

    const int tiles = (N + 63) / 64;
    const int egrid = (E + 255) / 256;
    const int nb    = (N + 1023) / 1024;
    const int agrid = (N + 15) / 16;   // 16 nodes/block (16-lane group per node)

    // ---- CSR build (once; graph static across the 3 layers)
    hipMemsetAsync(degI, 0, (size_t)N * sizeof(int), stream);
    hist_kernel<<<egrid, 256, 0, stream>>>(dst, degI, rank, E);
    scan_reduce<<<nb, 1024, 0, stream>>>(degI, bsums, N);
    scan_blocksums<<<1, 1024, 0, stream>>>(bsums, nb);
    scan_final<<<nb, 1024, 0, stream>>>(degI, bsums, offsets, N, E);
    fill_kernel<<<egrid, 256, 0, stream>>>(src, dst, offsets, rank, csr, E);

    // ---- 3 layers: gather-mean, then fused GEMM + epilogue
    aggregate_kernel<<<agrid, 256, 0, stream>>>(x, offsets, csr, AGG, N);
    node_update<0><<<tiles, 256, 0, stream>>>(x, AGG, Wl0, bl0, Wr0, g0, b0, A, N);

    aggregate_kernel<<<agrid, 256, 0, stream>>>(A, offsets, csr, AGG, N);
    node_update<0><<<tiles, 256, 0, stream>>>(A, AGG, Wl1, bl1, Wr1, g1, b1, B, N);

    aggregate_kernel<<<agrid, 256, 0, stream>>>(B, offsets, csr, AGG, N);
    node_update<1><<<tiles, 256, 0, stream>>>(B, AGG, Wl2, bl2, Wr2, nullptr, nullptr, out, N);
}

// Round 5
// 447.856 us; speedup vs baseline: 2.5481x; 1.0802x over previous
//
#include <hip/hip_runtime.h>

#define DD   64      // channels
#define KK   128     // fused GEMM K = 64 (mean) + 64 (h)
#define XSTR 132     // LDS X-tile row stride (128 + 4 pad -> breaks bank conflicts)

typedef unsigned int  uint32;
typedef unsigned short ushort16;

__device__ __forceinline__ unsigned short f2bf_rne(float f) {
    uint32 u = __float_as_uint(f);
    u += 0x7fffu + ((u >> 16) & 1u);   // round-to-nearest-even
    return (unsigned short)(u >> 16);
}
__device__ __forceinline__ float bf_lo(uint32 w) { return __uint_as_float(w << 16); }
__device__ __forceinline__ float bf_hi(uint32 w) { return __uint_as_float(w & 0xffff0000u); }

// ===========================================================================
// CSR build: histogram(+rank) -> exclusive scan (two-level) -> fill (no atomic)
// ===========================================================================
__global__ __launch_bounds__(256) void hist_kernel(const int* __restrict__ dst,
                                                   int* __restrict__ degI,
                                                   int* __restrict__ rank, int E) {
    int e = blockIdx.x * 256 + threadIdx.x;
    if (e < E) rank[e] = atomicAdd(&degI[dst[e]], 1);
}

__global__ __launch_bounds__(1024) void scan_reduce(const int* __restrict__ degI,
                                                    int* __restrict__ blockSums, int N) {
    __shared__ int s[1024];
    int t = threadIdx.x;
    int idx = blockIdx.x * 1024 + t;
    s[t] = (idx < N) ? degI[idx] : 0;
    __syncthreads();
    for (int d = 512; d > 0; d >>= 1) {
        if (t < d) s[t] += s[t + d];
        __syncthreads();
    }
    if (t == 0) blockSums[blockIdx.x] = s[0];
}

__global__ __launch_bounds__(1024) void scan_blocksums(int* __restrict__ blockSums, int nb) {
    __shared__ int s[1024];
    int t = threadIdx.x;
    s[t] = (t < nb) ? blockSums[t] : 0;
    __syncthreads();
    for (int d = 1; d < 1024; d <<= 1) {
        int v = (t >= d) ? s[t - d] : 0;
        __syncthreads();
        if (t >= d) s[t] += v;
        __syncthreads();
    }
    if (t < nb) blockSums[t] = (t == 0) ? 0 : s[t - 1];
}

__global__ __launch_bounds__(1024) void scan_final(const int* __restrict__ degI,
                                                   const int* __restrict__ blockSums,
                                                   int* __restrict__ offsets,
                                                   int N, int E) {
    __shared__ int s[1024];
    int t = threadIdx.x;
    int idx = blockIdx.x * 1024 + t;
    int val = (idx < N) ? degI[idx] : 0;
    s[t] = val;
    __syncthreads();
    for (int d = 1; d < 1024; d <<= 1) {
        int v = (t >= d) ? s[t - d] : 0;
        __syncthreads();
        if (t >= d) s[t] += v;
        __syncthreads();
    }
    if (idx < N) offsets[idx] = blockSums[blockIdx.x] + s[t] - val;   // exclusive
    if (blockIdx.x == 0 && t == 0) offsets[N] = E;
}

__global__ __launch_bounds__(256) void fill_kernel(const int* __restrict__ src,
                                                   const int* __restrict__ dst,
                                                   const int* __restrict__ offsets,
                                                   const int* __restrict__ rank,
                                                   int* __restrict__ csr, int E) {
    int e = blockIdx.x * 256 + threadIdx.x;
    if (e < E) {
        int pos = offsets[dst[e]] + rank[e];
        __builtin_nontemporal_store(src[e], &csr[pos]);
    }
}

// ===========================================================================
// x (fp32) -> bf16 shadow copy, vectorized
// ===========================================================================
__global__ __launch_bounds__(256) void cvt_kernel(const float* __restrict__ x,
                                                  unsigned short* __restrict__ xb,
                                                  int n4) {   // n/4
    int i = blockIdx.x * 256 + threadIdx.x;
    if (i < n4) {
        float4 v = ((const float4*)x)[i];
        ushort4 p;
        p.x = f2bf_rne(v.x); p.y = f2bf_rne(v.y);
        p.z = f2bf_rne(v.z); p.w = f2bf_rne(v.w);
        ((ushort4*)xb)[i] = p;
    }
}

// ===========================================================================
// Aggregation over bf16 rows: one 8-LANE GROUP per dst node (8 nodes/wave).
// Lane q owns uint4 chunk q (16 B = 8 bf16 channels) of the 128 B row.
// Neighbors in predicated batches of 8 -> 8 gathers in flight per lane.
// fp32 accumulate; writes the MEAN row to agg (fp32, coalesced).
// ===========================================================================
__global__ __launch_bounds__(256) void aggregate_kernel(
    const unsigned short* __restrict__ hb,  // [N,64] bf16
    const int* __restrict__ offsets,        // [N+1]
    const int* __restrict__ csr,            // [E]
    float* __restrict__ agg,                // [N,64] <- mean (fp32)
    int N) {
    int node = (blockIdx.x * 256 + threadIdx.x) >> 3;
    if (node >= N) return;
    const int q = threadIdx.x & 7;          // 16 B chunk within row

    const int off0 = offsets[node];
    const int off1 = offsets[node + 1];

    float a0 = 0.f, a1 = 0.f, a2 = 0.f, a3 = 0.f,
          a4 = 0.f, a5 = 0.f, a6 = 0.f, a7 = 0.f;

    for (int j = off0; j < off1; j += 8) {
        uint4 v[8];
#pragma unroll
        for (int s = 0; s < 8; ++s) {
            uint4 t = make_uint4(0u, 0u, 0u, 0u);
            int idx = j + s;
            if (idx < off1) {
                int sn = __builtin_nontemporal_load(&csr[idx]);
                t = ((const uint4*)(hb + (size_t)sn * DD))[q];
            }
            v[s] = t;
        }
#pragma unroll
        for (int s = 0; s < 8; ++s) {
            a0 += bf_lo(v[s].x); a1 += bf_hi(v[s].x);
            a2 += bf_lo(v[s].y); a3 += bf_hi(v[s].y);
            a4 += bf_lo(v[s].z); a5 += bf_hi(v[s].z);
            a6 += bf_lo(v[s].w); a7 += bf_hi(v[s].w);
        }
    }
    float invd = 1.0f / fmaxf((float)(off1 - off0), 1.0f);
    float4 lo = make_float4(a0 * invd, a1 * invd, a2 * invd, a3 * invd);
    float4 hi = make_float4(a4 * invd, a5 * invd, a6 * invd, a7 * invd);
    *(float4*)(&agg[(size_t)node * DD + q * 8])     = lo;
    *(float4*)(&agg[(size_t)node * DD + q * 8 + 4]) = hi;
}

// ===========================================================================
// Fused per-node update: out = [mean || h] @ [Wl ; Wr] + bl
//   MODE 0: h' = relu(LN(out)) + h   (also writes bf16 shadow outb)
//   MODE 1: h' = l2normalize(out + h)
// Block = 256 threads, tile = 64 nodes; thread computes 4 nodes x 4 cols.
// ===========================================================================
template <int MODE>
__global__ __launch_bounds__(256) void node_update(
    const float* __restrict__ h,    // [N,64] layer input (residual source)
    const float* __restrict__ mean, // [N,64] precomputed neighbor mean
    const float* __restrict__ Wl,   // [64,64] row-major
    const float* __restrict__ bl,   // [64]
    const float* __restrict__ Wr,   // [64,64]
    const float* __restrict__ g,    // [64] LN gamma (MODE 0)
    const float* __restrict__ b,    // [64] LN beta  (MODE 0)
    float* __restrict__ out,        // [N,64]
    unsigned short* __restrict__ outb, // [N,64] bf16 shadow (MODE 0)
    int nNodes) {
    __shared__ float sW[KK * DD];      // rows 0..63 = Wl, 64..127 = Wr  ([k][c])
    __shared__ float sX[64 * XSTR];    // [n][k]; k<64: mean row, k>=64: h row
    __shared__ float sbl[DD], sg[DD], sb[DD];

    const int t = threadIdx.x;

    for (int i = t; i < DD * DD; i += 256) {
        sW[i]           = Wl[i];
        sW[DD * DD + i] = Wr[i];
    }
    if (t < DD) {
        sbl[t] = bl[t];
        if (MODE == 0) { sg[t] = g[t]; sb[t] = b[t]; }
    }

    const int nbase = blockIdx.x * 64;

    for (int r = 0; r < 8; ++r) {
        int idx  = r * 256 + t;
        int node = idx >> 5;       // 0..63
        int q    = idx & 31;       // float4 within the 128-float row
        int n    = nbase + node;
        float4 v = make_float4(0.f, 0.f, 0.f, 0.f);
        if (n < nNodes) {
            v = (q < 16) ? ((const float4*)(mean + (size_t)n * DD))[q]
                         : ((const float4*)(h    + (size_t)n * DD))[q - 16];
        }
        *(float4*)(&sX[node * XSTR + q * 4]) = v;
    }
    __syncthreads();

    const int c0 = (t & 15) * 4;   // output cols c0..c0+3
    const int n0 = (t >> 4) * 4;   // nodes n0..n0+3 (within tile)

    float acc[4][4];
#pragma unroll
    for (int i = 0; i < 4; ++i)
#pragma unroll
        for (int j = 0; j < 4; ++j) acc[i][j] = sbl[c0 + j];

#pragma unroll 8
    for (int k = 0; k < KK; ++k) {
        const float4 w = *(const float4*)(&sW[k * DD + c0]);
#pragma unroll
        for (int i = 0; i < 4; ++i) {
            float xv = sX[(n0 + i) * XSTR + k];
            acc[i][0] = fmaf(xv, w.x, acc[i][0]);
            acc[i][1] = fmaf(xv, w.y, acc[i][1]);
            acc[i][2] = fmaf(xv, w.z, acc[i][2]);
            acc[i][3] = fmaf(xv, w.w, acc[i][3]);
        }
    }

    float res[4][4];
#pragma unroll
    for (int i = 0; i < 4; ++i) {
        float4 rv = *(const float4*)(&sX[(n0 + i) * XSTR + 64 + c0]);
        res[i][0] = rv.x; res[i][1] = rv.y; res[i][2] = rv.z; res[i][3] = rv.w;
    }

#pragma unroll
    for (int i = 0; i < 4; ++i) {
        int nn = nbase + n0 + i;
        float4 o;
        if (MODE == 0) {
            float s = acc[i][0] + acc[i][1] + acc[i][2] + acc[i][3];
            s += __shfl_xor(s, 1, 64);
            s += __shfl_xor(s, 2, 64);
            s += __shfl_xor(s, 4, 64);
            s += __shfl_xor(s, 8, 64);
            float mu = s * (1.0f / 64.0f);
            float d0 = acc[i][0] - mu, d1 = acc[i][1] - mu,
                  d2 = acc[i][2] - mu, d3 = acc[i][3] - mu;
            float qq = d0 * d0 + d1 * d1 + d2 * d2 + d3 * d3;
            qq += __shfl_xor(qq, 1, 64);
            qq += __shfl_xor(qq, 2, 64);
            qq += __shfl_xor(qq, 4, 64);
            qq += __shfl_xor(qq, 8, 64);
            float rstd = rsqrtf(qq * (1.0f / 64.0f) + 1e-5f);
            o.x = fmaxf(d0 * rstd * sg[c0 + 0] + sb[c0 + 0], 0.f) + res[i][0];
            o.y = fmaxf(d1 * rstd * sg[c0 + 1] + sb[c0 + 1], 0.f) + res[i][1];
            o.z = fmaxf(d2 * rstd * sg[c0 + 2] + sb[c0 + 2], 0.f) + res[i][2];
            o.w = fmaxf(d3 * rstd * sg[c0 + 3] + sb[c0 + 3], 0.f) + res[i][3];
        } else {
            float y0 = acc[i][0] + res[i][0], y1 = acc[i][1] + res[i][1],
                  y2 = acc[i][2] + res[i][2], y3 = acc[i][3] + res[i][3];
            float qq = y0 * y0 + y1 * y1 + y2 * y2 + y3 * y3;
            qq += __shfl_xor(qq, 1, 64);
            qq += __shfl_xor(qq, 2, 64);
            qq += __shfl_xor(qq, 4, 64);
            qq += __shfl_xor(qq, 8, 64);
            float inv = 1.0f / fmaxf(sqrtf(qq), 1e-12f);
            o.x = y0 * inv; o.y = y1 * inv; o.z = y2 * inv; o.w = y3 * inv;
        }
        if (nn < nNodes) {
            *(float4*)(&out[(size_t)nn * DD + c0]) = o;
            if (MODE == 0) {
                ushort4 p;
                p.x = f2bf_rne(o.x); p.y = f2bf_rne(o.y);
                p.z = f2bf_rne(o.z); p.w = f2bf_rne(o.w);
                *(ushort4*)(&outb[(size_t)nn * DD + c0]) = p;
            }
        }
    }
}

// ===========================================================================
extern "C" void kernel_launch(void* const* d_in, const int* in_sizes, int n_in,
                              void* d_out, int out_size, void* d_ws, size_t ws_size,
                              hipStream_t stream) {
    const float* x   = (const float*)d_in[0];
    const int*   ei  = (const int*)d_in[1];   // [2, E] int32: row0 = src, row1 = dst
    const float* Wl0 = (const float*)d_in[2];
    const float* bl0 = (const float*)d_in[3];
    const float* Wr0 = (const float*)d_in[4];
    const float* Wl1 = (const float*)d_in[5];
    const float* bl1 = (const float*)d_in[6];
    const float* Wr1 = (const float*)d_in[7];
    const float* Wl2 = (const float*)d_in[8];
    const float* bl2 = (const float*)d_in[9];
    const float* Wr2 = (const float*)d_in[10];
    const float* g0  = (const float*)d_in[11];
    const float* b0  = (const float*)d_in[12];
    const float* g1  = (const float*)d_in[13];
    const float* b1  = (const float*)d_in[14];

    const int N = in_sizes[0] / DD;   // 100000
    const int E = in_sizes[1] / 2;    // 1250000
    const int* src = ei;
    const int* dst = ei + E;

    // Workspace: A[N*64]f32 | B[N*64]f32 | AGG[N*64]f32 | HB[N*64]bf16
    //            | degI[N] | offsets[N+1] | bsums[1024] | csr[E]
    // rank[E] aliases AGG (consumed by fill before AGG is first written).
    float* A       = (float*)d_ws;
    float* B       = A + (size_t)N * DD;
    float* AGG     = B + (size_t)N * DD;
    int*   rank    = (int*)AGG;
    unsigned short* HB = (unsigned short*)(AGG + (size_t)N * DD);
    int*   degI    = (int*)(HB + (size_t)N * DD);
    int*   offsets = degI + N;
    int*   bsums   = offsets + (N + 1);
    int*   csr     = bsums + 1024;
    float* out     = (float*)d_out;

    const int tiles = (N + 63) / 64;
    const int egrid = (E + 255) / 256;
    const int nb    = (N + 1023) / 1024;
    const int agrid = (N + 31) / 32;   // 32 nodes/block (8-lane group per node)
    const int cgrid = (N * DD / 4 + 255) / 256;

    // ---- CSR build (once; graph static across the 3 layers)
    hipMemsetAsync(degI, 0, (size_t)N * sizeof(int), stream);
    hist_kernel<<<egrid, 256, 0, stream>>>(dst, degI, rank, E);
    scan_reduce<<<nb, 1024, 0, stream>>>(degI, bsums, N);
    scan_blocksums<<<1, 1024, 0, stream>>>(bsums, nb);
    scan_final<<<nb, 1024, 0, stream>>>(degI, bsums, offsets, N, E);
    fill_kernel<<<egrid, 256, 0, stream>>>(src, dst, offsets, rank, csr, E);

    // ---- layer 0 (x -> A); HB = bf16(x)
    cvt_kernel<<<cgrid, 256, 0, stream>>>(x, HB, N * DD / 4);
    aggregate_kernel<<<agrid, 256, 0, stream>>>(HB, offsets, csr, AGG, N);
    node_update<0><<<tiles, 256, 0, stream>>>(x, AGG, Wl0, bl0, Wr0, g0, b0, A, HB, N);

    // ---- layer 1 (A -> B); HB now bf16(A)
    aggregate_kernel<<<agrid, 256, 0, stream>>>(HB, offsets, csr, AGG, N);
    node_update<0><<<tiles, 256, 0, stream>>>(A, AGG, Wl1, bl1, Wr1, g1, b1, B, HB, N);

    // ---- layer 2 (B -> out); HB now bf16(B)
    aggregate_kernel<<<agrid, 256, 0, stream>>>(HB, offsets, csr, AGG, N);
    node_update<1><<<tiles, 256, 0, stream>>>(B, AGG, Wl2, bl2, Wr2, nullptr, nullptr, out, nullptr, N);
}